// Round 1
// 484.441 us; speedup vs baseline: 1.1012x; 1.1012x over previous
//
#include <hip/hip_runtime.h>
#include <hip/hip_bf16.h>
#include <stdint.h>

#define BATCH 32
#define CDIM  256
#define NPIX  4096
#define HEADS 8
#define KD    64
#define VD    64
#define OQ    512     // HEADS*KD
#define OTOT  640     // OQ + KD + VD

typedef __hip_bfloat16 bf16;
typedef __attribute__((ext_vector_type(8))) short bf16x8;   // MFMA A/B fragment (4 VGPRs)
typedef __attribute__((ext_vector_type(4))) float floatx4;  // MFMA C/D fragment

union pack8 { bf16 h[8]; uint4 u; };

__device__ inline uint4 cvt8(const float* __restrict__ s) {
  float4 f0 = *reinterpret_cast<const float4*>(s);
  float4 f1 = *reinterpret_cast<const float4*>(s + 4);
  pack8 t;
  t.h[0] = __float2bfloat16(f0.x); t.h[1] = __float2bfloat16(f0.y);
  t.h[2] = __float2bfloat16(f0.z); t.h[3] = __float2bfloat16(f0.w);
  t.h[4] = __float2bfloat16(f1.x); t.h[5] = __float2bfloat16(f1.y);
  t.h[6] = __float2bfloat16(f1.z); t.h[7] = __float2bfloat16(f1.w);
  return t.u;
}

// async global->LDS, 16B per lane; LDS dest is wave-uniform base + lane*16
__device__ inline void gload16(const bf16* g, bf16* l) {
  __builtin_amdgcn_global_load_lds(
      (const __attribute__((address_space(1))) void*)(g),
      (__attribute__((address_space(3))) void*)(l), 16, 0, 0);
}

// Swizzled LDS tile access: rows of 64 bf16 (128B); XOR byte bits 4..6 with row&7
// so 16 lanes reading consecutive rows at one column hit 8 distinct 16B slots.
__device__ inline bf16x8 lds_frag(const bf16* base, int row, int colbyte) {
  int off = row * 128 + (colbyte ^ ((row & 7) << 4));
  return *reinterpret_cast<const bf16x8*>(reinterpret_cast<const char*>(base) + off);
}
__device__ inline void ep_store(bf16* ep, int row, int colbyte, bf16 v) {
  int off = row * 128 + (colbyte ^ ((row & 7) << 4));
  *reinterpret_cast<bf16*>(reinterpret_cast<char*>(ep) + off) = v;
}

// ---------------------------------------------------------------------------
// Kernel P: pack Wq/Wk/Wv (fp32) -> Wqkv bf16 [640][256], once per launch
// ---------------------------------------------------------------------------
__global__ __launch_bounds__(256) void prep_w(const float* __restrict__ Wq,
                                              const float* __restrict__ Wk,
                                              const float* __restrict__ Wv,
                                              bf16* __restrict__ Wb) {
  int i = blockIdx.x * 256 + threadIdx.x;   // 20480 chunks of 8 elements
  int o = i >> 5;                            // 32 chunks per 256-wide row
  int off = (i & 31) * 8;
  const float* src = (o < OQ)      ? (Wq + (size_t)o * CDIM + off)
                   : (o < OQ + KD) ? (Wk + (size_t)(o - OQ) * CDIM + off)
                                   : (Wv + (size_t)(o - OQ - KD) * CDIM + off);
  *reinterpret_cast<uint4*>(Wb + (size_t)o * CDIM + off) = cvt8(src);
}

// ---------------------------------------------------------------------------
// Kernel T: x (b,C,N) fp32 -> xT (b,N,C) bf16, 64x64 tiles through LDS
// ---------------------------------------------------------------------------
__global__ __launch_bounds__(256) void transpose_k(const float* __restrict__ x,
                                                   bf16* __restrict__ xT) {
  __shared__ bf16 t[64 * 72];
  const int tid = threadIdx.x;
  const int b = blockIdx.z;
  const int n0 = blockIdx.x * 64;
  const int c0 = blockIdx.y * 64;
  const float* xb = x + (size_t)b * CDIM * NPIX;
  for (int p = 0; p < 2; ++p) {
    int cl = p * 32 + (tid >> 3);
    int no = (tid & 7) * 8;
    *reinterpret_cast<uint4*>(&t[cl * 72 + no]) =
        cvt8(xb + (size_t)(c0 + cl) * NPIX + n0 + no);
  }
  __syncthreads();
  bf16* xTb = xT + (size_t)b * NPIX * CDIM;
  for (int p = 0; p < 2; ++p) {
    int nl = p * 32 + (tid >> 3);
    int co = (tid & 7) * 8;
    pack8 tmp;
    for (int j = 0; j < 8; ++j) tmp.h[j] = t[(co + j) * 72 + nl];
    *reinterpret_cast<uint4*>(xTb + (size_t)(n0 + nl) * CDIM + c0 + co) = tmp.u;
  }
}

// ---------------------------------------------------------------------------
// Kernel G1: qkvT = xT (4096x256,bf16) * Wqkv^T (bf16)  -> (4096 x 640)
//   global_load_lds staging, swizzled LDS (linear dest + inv-swz source).
//   cols 0..511: q + fused softmax over each 64-col head group -> qT (bf16)
//   cols 512..575: k -> kT ; cols 576..639: v -> vT   (n-major, bf16)
// ---------------------------------------------------------------------------
__global__ __launch_bounds__(256, 2) void gemm_qkv(
    const bf16* __restrict__ xT, const bf16* __restrict__ Wb,
    const float* __restrict__ bq, const float* __restrict__ bk,
    const float* __restrict__ bv,
    bf16* __restrict__ qT, bf16* __restrict__ kT, bf16* __restrict__ vT) {
  __shared__ bf16 lsA[128 * 64];
  __shared__ bf16 lsB[128 * 64];
  const int tid = threadIdx.x;
  const int b  = blockIdx.z;
  const int bm = blockIdx.x;   // n-tile (M dim): 0..31
  const int ot = blockIdx.y;   // o-tile (N dim): 0..4
  const int lane = tid & 63;
  const int w    = tid >> 6;
  const int wm = w & 1, wn = w >> 1;
  const int l15 = lane & 15, quad = lane >> 4;

  const bf16* Ab = xT + (size_t)b * NPIX * CDIM + (size_t)bm * 128 * CDIM;
  const bf16* Bb = Wb + (size_t)ot * 128 * CDIM;

  const int sr = lane >> 3;   // row within an 8-row staging group
  const int sc = lane & 7;    // swizzled 16B chunk index this lane fills

  floatx4 acc[4][4];
  const floatx4 zf = {0.f, 0.f, 0.f, 0.f};
  for (int i = 0; i < 4; ++i)
    for (int j = 0; j < 4; ++j) acc[i][j] = zf;

  for (int kb = 0; kb < CDIM / 64; ++kb) {
    __syncthreads();
#pragma unroll
    for (int it = 0; it < 4; ++it) {
      const int r = w * 32 + it * 8 + sr;
      const int c16 = sc ^ (r & 7);            // inverse swizzle on the SOURCE
      gload16(Ab + (size_t)r * CDIM + kb * 64 + c16 * 8, &lsA[(w * 4 + it) * 512]);
      gload16(Bb + (size_t)r * CDIM + kb * 64 + c16 * 8, &lsB[(w * 4 + it) * 512]);
    }
    __syncthreads();   // drains vmcnt before barrier (compiler-enforced)
#pragma unroll
    for (int kk = 0; kk < 64; kk += 32) {
      bf16x8 af[4], bfr[4];
      for (int mi = 0; mi < 4; ++mi)
        af[mi] = lds_frag(lsA, wm * 64 + mi * 16 + l15, kk * 2 + quad * 16);
      for (int ni = 0; ni < 4; ++ni)
        bfr[ni] = lds_frag(lsB, wn * 64 + ni * 16 + l15, kk * 2 + quad * 16);
      for (int mi = 0; mi < 4; ++mi)
        for (int ni = 0; ni < 4; ++ni)
          acc[mi][ni] = __builtin_amdgcn_mfma_f32_16x16x32_bf16(af[mi], bfr[ni], acc[mi][ni], 0, 0, 0);
    }
  }
  __syncthreads();

  // epilogue: this wave owns 64 rows (n) x 64 cols (o); reuse staging LDS
  bf16* ep = ((w < 2) ? lsA : lsB) + (w & 1) * (64 * 64);
  const int obase = ot * 128 + wn * 64;

  if (obase < 512) {   // q head group: softmax over the 64 cols, per row
    float bias[4];
    for (int ni = 0; ni < 4; ++ni) bias[ni] = bq[obase + ni * 16 + l15];
    for (int mi = 0; mi < 4; ++mi) {
      for (int r = 0; r < 4; ++r) {
        float v0 = acc[mi][0][r] + bias[0];
        float v1 = acc[mi][1][r] + bias[1];
        float v2 = acc[mi][2][r] + bias[2];
        float v3 = acc[mi][3][r] + bias[3];
        float m = fmaxf(fmaxf(v0, v1), fmaxf(v2, v3));
        for (int off = 1; off < 16; off <<= 1) m = fmaxf(m, __shfl_xor(m, off));
        float e0 = __expf(v0 - m), e1 = __expf(v1 - m);
        float e2 = __expf(v2 - m), e3 = __expf(v3 - m);
        float s = e0 + e1 + e2 + e3;
        for (int off = 1; off < 16; off <<= 1) s += __shfl_xor(s, off);
        float inv = 1.0f / s;
        int lr = mi * 16 + quad * 4 + r;
        ep_store(ep, lr, ( 0 + l15) * 2, __float2bfloat16(e0 * inv));
        ep_store(ep, lr, (16 + l15) * 2, __float2bfloat16(e1 * inv));
        ep_store(ep, lr, (32 + l15) * 2, __float2bfloat16(e2 * inv));
        ep_store(ep, lr, (48 + l15) * 2, __float2bfloat16(e3 * inv));
      }
    }
  } else {             // k (wn==0) or v (wn==1): bias add, raw write
    const float* bp = (wn == 0) ? bk : bv;
    float bias[4];
    for (int ni = 0; ni < 4; ++ni) bias[ni] = bp[ni * 16 + l15];
    for (int mi = 0; mi < 4; ++mi)
      for (int r = 0; r < 4; ++r) {
        int lr = mi * 16 + quad * 4 + r;
        for (int ni = 0; ni < 4; ++ni)
          ep_store(ep, lr, (ni * 16 + l15) * 2,
                   __float2bfloat16(acc[mi][ni][r] + bias[ni]));
      }
  }
  __syncthreads();

  // cooperative coalesced copy-out of this wave's 64x64 region
  bf16* dst; int rstride;
  const int row0 = bm * 128 + wm * 64;
  if (obase < 512)      { dst = qT + (size_t)b * NPIX * OQ + (size_t)row0 * OQ + obase; rstride = OQ; }
  else if (obase == 512){ dst = kT + (size_t)b * NPIX * KD + (size_t)row0 * KD;         rstride = KD; }
  else                  { dst = vT + (size_t)b * NPIX * VD + (size_t)row0 * VD;         rstride = VD; }
  for (int p = 0; p < 8; ++p) {
    int lr = (lane >> 3) + p * 8;
    int cb = (lane & 7) * 16;   // byte column
    int off = lr * 128 + (cb ^ ((lr & 7) << 4));
    uint4 v = *reinterpret_cast<const uint4*>(reinterpret_cast<const char*>(ep) + off);
    *reinterpret_cast<uint4*>(dst + (size_t)lr * rstride + (cb >> 1)) = v;
  }
}

// ---------------------------------------------------------------------------
// Kernel CTX: ctx_num[b][d][e] = sum_n exp(k[d,n]) * v[e,n] ; denom[b][d]
// ---------------------------------------------------------------------------
__global__ __launch_bounds__(256) void ctx_partial(const bf16* __restrict__ kT,
                                                   const bf16* __restrict__ vT,
                                                   float* __restrict__ ctxn,
                                                   float* __restrict__ dnm) {
  __shared__ float ek[16 * 68];
  __shared__ float vv[16 * 68];
  const int tid = threadIdx.x;
  const int b = blockIdx.y, ci = blockIdx.x;
  const int dg = tid >> 4, eg = tid & 15;
  float acc[4][4] = {};
  float dloc = 0.f;
  for (int nb = 0; nb < 16; ++nb) {
    const int n0 = ci * 256 + nb * 16;
    __syncthreads();
    if (tid < 128) {
      int r = tid >> 3, off = (tid & 7) * 8;
      const bf16* src = kT + (size_t)b * NPIX * KD + (size_t)(n0 + r) * KD + off;
      for (int j = 0; j < 8; ++j) ek[r * 68 + off + j] = __expf(__bfloat162float(src[j]));
    } else {
      int t2 = tid - 128;
      int r = t2 >> 3, off = (t2 & 7) * 8;
      const bf16* src = vT + (size_t)b * NPIX * VD + (size_t)(n0 + r) * VD + off;
      for (int j = 0; j < 8; ++j) vv[r * 68 + off + j] = __bfloat162float(src[j]);
    }
    __syncthreads();
    for (int nn = 0; nn < 16; ++nn) {
      float4 e4 = *reinterpret_cast<const float4*>(&ek[nn * 68 + dg * 4]);
      float4 v4 = *reinterpret_cast<const float4*>(&vv[nn * 68 + eg * 4]);
      acc[0][0] += e4.x * v4.x; acc[0][1] += e4.x * v4.y; acc[0][2] += e4.x * v4.z; acc[0][3] += e4.x * v4.w;
      acc[1][0] += e4.y * v4.x; acc[1][1] += e4.y * v4.y; acc[1][2] += e4.y * v4.z; acc[1][3] += e4.y * v4.w;
      acc[2][0] += e4.z * v4.x; acc[2][1] += e4.z * v4.y; acc[2][2] += e4.z * v4.z; acc[2][3] += e4.z * v4.w;
      acc[3][0] += e4.w * v4.x; acc[3][1] += e4.w * v4.y; acc[3][2] += e4.w * v4.z; acc[3][3] += e4.w * v4.w;
    }
    if (tid < 64) {
      for (int nn = 0; nn < 16; ++nn) dloc += ek[nn * 68 + tid];
    }
  }
  for (int i = 0; i < 4; ++i)
    for (int j = 0; j < 4; ++j)
      atomicAdd(&ctxn[(size_t)b * 4096 + (dg * 4 + i) * 64 + eg * 4 + j], acc[i][j]);
  if (tid < 64) atomicAdd(&dnm[b * 64 + tid], dloc);
}

// ---------------------------------------------------------------------------
// Kernel MBUILD: M[b][c][h*64+d] = sum_e Wo[c][h*64+e] * ctx[d][e]/denom[d]
// ---------------------------------------------------------------------------
__global__ __launch_bounds__(256) void mbuild(const float* __restrict__ ctxn,
                                              const float* __restrict__ dnm,
                                              const float* __restrict__ Wo,
                                              bf16* __restrict__ Mm) {
  __shared__ float cn[64 * 68];
  const int h = blockIdx.x, b = blockIdx.y, tid = threadIdx.x;
  for (int ii = tid; ii < 4096; ii += 256) {
    int d = ii >> 6;
    cn[d * 68 + (ii & 63)] = ctxn[(size_t)b * 4096 + ii] / dnm[b * 64 + d];
  }
  __syncthreads();
  const int c = tid;
  const float* wrow = Wo + (size_t)c * OQ + h * 64;
  float wv[64];
  for (int e = 0; e < 64; ++e) wv[e] = wrow[e];
  bf16* mrow = Mm + (size_t)b * CDIM * OQ + (size_t)c * OQ + h * 64;
  for (int d = 0; d < 64; ++d) {
    float a = 0.f;
    for (int e = 0; e < 64; ++e) a += wv[e] * cn[d * 68 + e];
    mrow[d] = __float2bfloat16(a);
  }
}

// ---------------------------------------------------------------------------
// Kernel G2: y[b] (256x4096, fp32) = M_b (256x512) * q_smT^T + bo -> d_out
//   global_load_lds staging + swizzled LDS, same as G1.
// ---------------------------------------------------------------------------
__global__ __launch_bounds__(256, 2) void gemm_out(
    const bf16* __restrict__ Mm, const bf16* __restrict__ qT,
    const float* __restrict__ bo, float* __restrict__ out) {
  __shared__ bf16 lsA[128 * 64];
  __shared__ bf16 lsB[128 * 64];
  const int tid = threadIdx.x;
  const int b  = blockIdx.z;
  const int cm = blockIdx.x;   // c-tile: 0..1
  const int nt = blockIdx.y;   // n-tile: 0..31
  const int lane = tid & 63;
  const int w    = tid >> 6;
  const int wm = w & 1, wn = w >> 1;
  const int l15 = lane & 15, quad = lane >> 4;

  const bf16* Ab = Mm + (size_t)b * CDIM * OQ + (size_t)cm * 128 * OQ;
  const bf16* Bb = qT + (size_t)b * NPIX * OQ + (size_t)nt * 128 * OQ;

  const int sr = lane >> 3;
  const int sc = lane & 7;

  floatx4 acc[4][4];
  const floatx4 zf = {0.f, 0.f, 0.f, 0.f};
  for (int i = 0; i < 4; ++i)
    for (int j = 0; j < 4; ++j) acc[i][j] = zf;

  for (int kb = 0; kb < OQ / 64; ++kb) {
    __syncthreads();
#pragma unroll
    for (int it = 0; it < 4; ++it) {
      const int r = w * 32 + it * 8 + sr;
      const int c16 = sc ^ (r & 7);
      gload16(Ab + (size_t)r * OQ + kb * 64 + c16 * 8, &lsA[(w * 4 + it) * 512]);
      gload16(Bb + (size_t)r * OQ + kb * 64 + c16 * 8, &lsB[(w * 4 + it) * 512]);
    }
    __syncthreads();
#pragma unroll
    for (int kk = 0; kk < 64; kk += 32) {
      bf16x8 af[4], bfr[4];
      for (int mi = 0; mi < 4; ++mi)
        af[mi] = lds_frag(lsA, wm * 64 + mi * 16 + l15, kk * 2 + quad * 16);
      for (int ni = 0; ni < 4; ++ni)
        bfr[ni] = lds_frag(lsB, wn * 64 + ni * 16 + l15, kk * 2 + quad * 16);
      for (int mi = 0; mi < 4; ++mi)
        for (int ni = 0; ni < 4; ++ni)
          acc[mi][ni] = __builtin_amdgcn_mfma_f32_16x16x32_bf16(af[mi], bfr[ni], acc[mi][ni], 0, 0, 0);
    }
  }

  // epilogue: direct fp32 stores (rows = c with stride NPIX, cols = n)
  const int row0 = cm * 128 + wm * 64;
  const int col0 = nt * 128 + wn * 64;
  float* outb = out + (size_t)b * CDIM * NPIX;
  for (int mi = 0; mi < 4; ++mi)
    for (int r = 0; r < 4; ++r) {
      int c = row0 + mi * 16 + quad * 4 + r;
      float bias = bo[c];
      float* orow = outb + (size_t)c * NPIX + col0;
      for (int ni = 0; ni < 4; ++ni)
        orow[ni * 16 + l15] = acc[mi][ni][r] + bias;
    }
}

// ---------------------------------------------------------------------------
// Host
// ---------------------------------------------------------------------------
extern "C" void kernel_launch(void* const* d_in, const int* in_sizes, int n_in,
                              void* d_out, int out_size, void* d_ws, size_t ws_size,
                              hipStream_t stream) {
  const float* x  = (const float*)d_in[0];
  const float* Wq = (const float*)d_in[1];
  const float* bq = (const float*)d_in[2];
  const float* Wk = (const float*)d_in[3];
  const float* bk = (const float*)d_in[4];
  const float* Wv = (const float*)d_in[5];
  const float* bv = (const float*)d_in[6];
  const float* Wo = (const float*)d_in[7];
  const float* bo = (const float*)d_in[8];
  float* out = (float*)d_out;

  const size_t pb_W   = (size_t)OTOT * CDIM * 2;   //   327,680 (once)
  const size_t pb_xT  = (size_t)NPIX * CDIM * 2;   // 2,097,152
  const size_t pb_qT  = (size_t)NPIX * OQ * 2;     // 4,194,304
  const size_t pb_kT  = (size_t)NPIX * KD * 2;     //   524,288
  const size_t pb_vT  = (size_t)NPIX * VD * 2;     //   524,288
  const size_t pb_ctx = (size_t)KD * VD * 4;       //    16,384
  const size_t pb_dnm = (size_t)KD * 4;            //       256
  const size_t pb_Mm  = (size_t)CDIM * OQ * 2;     //   262,144
  const size_t perB = pb_xT + pb_qT + pb_kT + pb_vT + pb_ctx + pb_dnm + pb_Mm;

  int CB = 32;
  while (CB > 1 && (size_t)CB * perB + pb_W > ws_size) CB >>= 1;

  char* ws = (char*)d_ws;
  bf16*  Wb   = (bf16*)ws;                                  ws += pb_W;
  bf16*  xT   = (bf16*)ws;                                  ws += (size_t)CB * pb_xT;
  bf16*  qT   = (bf16*)ws;                                  ws += (size_t)CB * pb_qT;
  bf16*  kT   = (bf16*)ws;                                  ws += (size_t)CB * pb_kT;
  bf16*  vT   = (bf16*)ws;                                  ws += (size_t)CB * pb_vT;
  float* ctxn = (float*)ws;                                 ws += (size_t)CB * pb_ctx;
  float* dnm  = (float*)ws;                                 ws += (size_t)CB * pb_dnm;
  bf16*  Mm   = (bf16*)ws;

  prep_w<<<dim3(80), 256, 0, stream>>>(Wq, Wk, Wv, Wb);

  for (int b0 = 0; b0 < BATCH; b0 += CB) {
    const float* x_c  = x   + (size_t)b0 * CDIM * NPIX;
    float*      out_c = out + (size_t)b0 * CDIM * NPIX;
    hipMemsetAsync(ctxn, 0, (size_t)CB * (pb_ctx + pb_dnm), stream);
    transpose_k<<<dim3(64, 4, CB), 256, 0, stream>>>(x_c, xT);
    gemm_qkv<<<dim3(32, 5, CB), 256, 0, stream>>>(xT, Wb, bq, bk, bv, qT, kT, vT);
    ctx_partial<<<dim3(16, CB), 256, 0, stream>>>(kT, vT, ctxn, dnm);
    mbuild<<<dim3(HEADS, CB), 256, 0, stream>>>(ctxn, dnm, Wo, Mm);
    gemm_out<<<dim3(2, 32, CB), 256, 0, stream>>>(Mm, qT, bo, out_c);
  }
}

// Round 2
// 465.908 us; speedup vs baseline: 1.1450x; 1.0398x over previous
//
#include <hip/hip_runtime.h>
#include <hip/hip_bf16.h>
#include <stdint.h>

#define BATCH 32
#define CDIM  256
#define NPIX  4096
#define HEADS 8
#define KD    64
#define VD    64
#define OQ    512     // HEADS*KD
#define OTOT  640     // OQ + KD + VD

typedef __hip_bfloat16 bf16;
typedef __attribute__((ext_vector_type(8))) short bf16x8;   // MFMA A/B fragment (4 VGPRs)
typedef __attribute__((ext_vector_type(4))) float floatx4;  // MFMA C/D fragment

union pack8 { bf16 h[8]; uint4 u; };

__device__ inline uint4 cvt8(const float* __restrict__ s) {
  float4 f0 = *reinterpret_cast<const float4*>(s);
  float4 f1 = *reinterpret_cast<const float4*>(s + 4);
  pack8 t;
  t.h[0] = __float2bfloat16(f0.x); t.h[1] = __float2bfloat16(f0.y);
  t.h[2] = __float2bfloat16(f0.z); t.h[3] = __float2bfloat16(f0.w);
  t.h[4] = __float2bfloat16(f1.x); t.h[5] = __float2bfloat16(f1.y);
  t.h[6] = __float2bfloat16(f1.z); t.h[7] = __float2bfloat16(f1.w);
  return t.u;
}

// async global->LDS, 16B per lane; LDS dest is wave-uniform base + lane*16
__device__ inline void gload16(const bf16* g, bf16* l) {
  __builtin_amdgcn_global_load_lds(
      (const __attribute__((address_space(1))) void*)(g),
      (__attribute__((address_space(3))) void*)(l), 16, 0, 0);
}

// Swizzled LDS tile access: rows of 64 bf16 (128B); XOR byte bits 4..6 with row&7
__device__ inline bf16x8 lds_frag(const bf16* base, int row, int colbyte) {
  int off = row * 128 + (colbyte ^ ((row & 7) << 4));
  return *reinterpret_cast<const bf16x8*>(reinterpret_cast<const char*>(base) + off);
}
__device__ inline void ep_store(bf16* ep, int row, int colbyte, bf16 v) {
  int off = row * 128 + (colbyte ^ ((row & 7) << 4));
  *reinterpret_cast<bf16*>(reinterpret_cast<char*>(ep) + off) = v;
}

// ---------------------------------------------------------------------------
// Kernel P: pack Wq/Wk/Wv (fp32) -> Wqkv bf16 [640][256], once per launch
// ---------------------------------------------------------------------------
__global__ __launch_bounds__(256) void prep_w(const float* __restrict__ Wq,
                                              const float* __restrict__ Wk,
                                              const float* __restrict__ Wv,
                                              bf16* __restrict__ Wb) {
  int i = blockIdx.x * 256 + threadIdx.x;   // 20480 chunks of 8 elements
  int o = i >> 5;                            // 32 chunks per 256-wide row
  int off = (i & 31) * 8;
  const float* src = (o < OQ)      ? (Wq + (size_t)o * CDIM + off)
                   : (o < OQ + KD) ? (Wk + (size_t)(o - OQ) * CDIM + off)
                                   : (Wv + (size_t)(o - OQ - KD) * CDIM + off);
  *reinterpret_cast<uint4*>(Wb + (size_t)o * CDIM + off) = cvt8(src);
}

// ---------------------------------------------------------------------------
// Kernel T: x (b,C,N) fp32 -> xT (b,N,C) bf16, 64x64 tiles through LDS
// ---------------------------------------------------------------------------
__global__ __launch_bounds__(256) void transpose_k(const float* __restrict__ x,
                                                   bf16* __restrict__ xT) {
  __shared__ bf16 t[64 * 72];
  const int tid = threadIdx.x;
  const int b = blockIdx.z;
  const int n0 = blockIdx.x * 64;
  const int c0 = blockIdx.y * 64;
  const float* xb = x + (size_t)b * CDIM * NPIX;
  for (int p = 0; p < 2; ++p) {
    int cl = p * 32 + (tid >> 3);
    int no = (tid & 7) * 8;
    *reinterpret_cast<uint4*>(&t[cl * 72 + no]) =
        cvt8(xb + (size_t)(c0 + cl) * NPIX + n0 + no);
  }
  __syncthreads();
  bf16* xTb = xT + (size_t)b * NPIX * CDIM;
  for (int p = 0; p < 2; ++p) {
    int nl = p * 32 + (tid >> 3);
    int co = (tid & 7) * 8;
    pack8 tmp;
    for (int j = 0; j < 8; ++j) tmp.h[j] = t[(co + j) * 72 + nl];
    *reinterpret_cast<uint4*>(xTb + (size_t)(n0 + nl) * CDIM + c0 + co) = tmp.u;
  }
}

// ---------------------------------------------------------------------------
// Kernel G1: qkvT = xT (4096x256,bf16) * Wqkv^T (bf16)  -> (4096 x 640)
//   global_load_lds staging, swizzled LDS (linear dest + inv-swz source).
//   q epilogue: softmax WITHOUT max-shift (shift-invariant; |q|<~7 fp32-safe)
// ---------------------------------------------------------------------------
__global__ __launch_bounds__(256, 4) void gemm_qkv(
    const bf16* __restrict__ xT, const bf16* __restrict__ Wb,
    const float* __restrict__ bq, const float* __restrict__ bk,
    const float* __restrict__ bv,
    bf16* __restrict__ qT, bf16* __restrict__ kT, bf16* __restrict__ vT) {
  __shared__ bf16 lsA[128 * 64];
  __shared__ bf16 lsB[128 * 64];
  const int tid = threadIdx.x;
  const int b  = blockIdx.z;
  const int bm = blockIdx.x;   // n-tile (M dim): 0..31
  const int ot = blockIdx.y;   // o-tile (N dim): 0..4
  const int lane = tid & 63;
  const int w    = tid >> 6;
  const int wm = w & 1, wn = w >> 1;
  const int l15 = lane & 15, quad = lane >> 4;

  const bf16* Ab = xT + (size_t)b * NPIX * CDIM + (size_t)bm * 128 * CDIM;
  const bf16* Bb = Wb + (size_t)ot * 128 * CDIM;

  const int sr = lane >> 3;   // row within an 8-row staging group
  const int sc = lane & 7;    // swizzled 16B chunk index this lane fills

  floatx4 acc[4][4];
  const floatx4 zf = {0.f, 0.f, 0.f, 0.f};
  for (int i = 0; i < 4; ++i)
    for (int j = 0; j < 4; ++j) acc[i][j] = zf;

  for (int kb = 0; kb < CDIM / 64; ++kb) {
    __syncthreads();
#pragma unroll
    for (int it = 0; it < 4; ++it) {
      const int r = w * 32 + it * 8 + sr;
      const int c16 = sc ^ (r & 7);            // inverse swizzle on the SOURCE
      gload16(Ab + (size_t)r * CDIM + kb * 64 + c16 * 8, &lsA[(w * 4 + it) * 512]);
      gload16(Bb + (size_t)r * CDIM + kb * 64 + c16 * 8, &lsB[(w * 4 + it) * 512]);
    }
    __syncthreads();
#pragma unroll
    for (int kk = 0; kk < 64; kk += 32) {
      bf16x8 af[4], bfr[4];
      for (int mi = 0; mi < 4; ++mi)
        af[mi] = lds_frag(lsA, wm * 64 + mi * 16 + l15, kk * 2 + quad * 16);
      for (int ni = 0; ni < 4; ++ni)
        bfr[ni] = lds_frag(lsB, wn * 64 + ni * 16 + l15, kk * 2 + quad * 16);
      for (int mi = 0; mi < 4; ++mi)
        for (int ni = 0; ni < 4; ++ni)
          acc[mi][ni] = __builtin_amdgcn_mfma_f32_16x16x32_bf16(af[mi], bfr[ni], acc[mi][ni], 0, 0, 0);
    }
  }
  __syncthreads();

  // epilogue: this wave owns 64 rows (n) x 64 cols (o); reuse staging LDS
  bf16* ep = ((w < 2) ? lsA : lsB) + (w & 1) * (64 * 64);
  const int obase = ot * 128 + wn * 64;

  if (obase < 512) {   // q head group: softmax over the 64 cols, no max-shift
    float bias[4];
    for (int ni = 0; ni < 4; ++ni) bias[ni] = bq[obase + ni * 16 + l15];
    for (int mi = 0; mi < 4; ++mi) {
      for (int r = 0; r < 4; ++r) {
        float e0 = __expf(acc[mi][0][r] + bias[0]);
        float e1 = __expf(acc[mi][1][r] + bias[1]);
        float e2 = __expf(acc[mi][2][r] + bias[2]);
        float e3 = __expf(acc[mi][3][r] + bias[3]);
        float s = (e0 + e1) + (e2 + e3);
        for (int off = 1; off < 16; off <<= 1) s += __shfl_xor(s, off);
        float inv = 1.0f / s;
        int lr = mi * 16 + quad * 4 + r;
        ep_store(ep, lr, ( 0 + l15) * 2, __float2bfloat16(e0 * inv));
        ep_store(ep, lr, (16 + l15) * 2, __float2bfloat16(e1 * inv));
        ep_store(ep, lr, (32 + l15) * 2, __float2bfloat16(e2 * inv));
        ep_store(ep, lr, (48 + l15) * 2, __float2bfloat16(e3 * inv));
      }
    }
  } else {             // k (wn==0) or v (wn==1): bias add, raw write
    const float* bp = (wn == 0) ? bk : bv;
    float bias[4];
    for (int ni = 0; ni < 4; ++ni) bias[ni] = bp[ni * 16 + l15];
    for (int mi = 0; mi < 4; ++mi)
      for (int r = 0; r < 4; ++r) {
        int lr = mi * 16 + quad * 4 + r;
        for (int ni = 0; ni < 4; ++ni)
          ep_store(ep, lr, (ni * 16 + l15) * 2,
                   __float2bfloat16(acc[mi][ni][r] + bias[ni]));
      }
  }
  __syncthreads();

  // cooperative coalesced copy-out of this wave's 64x64 region
  bf16* dst; int rstride;
  const int row0 = bm * 128 + wm * 64;
  if (obase < 512)      { dst = qT + (size_t)b * NPIX * OQ + (size_t)row0 * OQ + obase; rstride = OQ; }
  else if (obase == 512){ dst = kT + (size_t)b * NPIX * KD + (size_t)row0 * KD;         rstride = KD; }
  else                  { dst = vT + (size_t)b * NPIX * VD + (size_t)row0 * VD;         rstride = VD; }
  for (int p = 0; p < 8; ++p) {
    int lr = (lane >> 3) + p * 8;
    int cb = (lane & 7) * 16;   // byte column
    int off = lr * 128 + (cb ^ ((lr & 7) << 4));
    uint4 v = *reinterpret_cast<const uint4*>(reinterpret_cast<const char*>(ep) + off);
    *reinterpret_cast<uint4*>(dst + (size_t)lr * rstride + (cb >> 1)) = v;
  }
}

// ---------------------------------------------------------------------------
// Kernel CTX: ctx_num[b][d][e] = sum_n exp(k[d,n]) * v[e,n] ; denom[b][d]
// ---------------------------------------------------------------------------
__global__ __launch_bounds__(256) void ctx_partial(const bf16* __restrict__ kT,
                                                   const bf16* __restrict__ vT,
                                                   float* __restrict__ ctxn,
                                                   float* __restrict__ dnm) {
  __shared__ float ek[16 * 68];
  __shared__ float vv[16 * 68];
  const int tid = threadIdx.x;
  const int b = blockIdx.y, ci = blockIdx.x;
  const int dg = tid >> 4, eg = tid & 15;
  float acc[4][4] = {};
  float dloc = 0.f;
  for (int nb = 0; nb < 16; ++nb) {
    const int n0 = ci * 256 + nb * 16;
    __syncthreads();
    if (tid < 128) {
      int r = tid >> 3, off = (tid & 7) * 8;
      const bf16* src = kT + (size_t)b * NPIX * KD + (size_t)(n0 + r) * KD + off;
      for (int j = 0; j < 8; ++j) ek[r * 68 + off + j] = __expf(__bfloat162float(src[j]));
    } else {
      int t2 = tid - 128;
      int r = t2 >> 3, off = (t2 & 7) * 8;
      const bf16* src = vT + (size_t)b * NPIX * VD + (size_t)(n0 + r) * VD + off;
      for (int j = 0; j < 8; ++j) vv[r * 68 + off + j] = __bfloat162float(src[j]);
    }
    __syncthreads();
    for (int nn = 0; nn < 16; ++nn) {
      float4 e4 = *reinterpret_cast<const float4*>(&ek[nn * 68 + dg * 4]);
      float4 v4 = *reinterpret_cast<const float4*>(&vv[nn * 68 + eg * 4]);
      acc[0][0] += e4.x * v4.x; acc[0][1] += e4.x * v4.y; acc[0][2] += e4.x * v4.z; acc[0][3] += e4.x * v4.w;
      acc[1][0] += e4.y * v4.x; acc[1][1] += e4.y * v4.y; acc[1][2] += e4.y * v4.z; acc[1][3] += e4.y * v4.w;
      acc[2][0] += e4.z * v4.x; acc[2][1] += e4.z * v4.y; acc[2][2] += e4.z * v4.z; acc[2][3] += e4.z * v4.w;
      acc[3][0] += e4.w * v4.x; acc[3][1] += e4.w * v4.y; acc[3][2] += e4.w * v4.z; acc[3][3] += e4.w * v4.w;
    }
    if (tid < 64) {
      for (int nn = 0; nn < 16; ++nn) dloc += ek[nn * 68 + tid];
    }
  }
  for (int i = 0; i < 4; ++i)
    for (int j = 0; j < 4; ++j)
      atomicAdd(&ctxn[(size_t)b * 4096 + (dg * 4 + i) * 64 + eg * 4 + j], acc[i][j]);
  if (tid < 64) atomicAdd(&dnm[b * 64 + tid], dloc);
}

// ---------------------------------------------------------------------------
// Kernel MBUILD: M[b][c][h*64+d] = sum_e Wo[c][h*64+e] * ctx[d][e]/denom[d]
//   split d across blockIdx.z; float4 LDS reads; 4 independent accumulators
// ---------------------------------------------------------------------------
__global__ __launch_bounds__(256) void mbuild(const float* __restrict__ ctxn,
                                              const float* __restrict__ dnm,
                                              const float* __restrict__ Wo,
                                              bf16* __restrict__ Mm) {
  __shared__ float cn[32 * 68];
  const int h = blockIdx.x, b = blockIdx.y, dz = blockIdx.z;
  const int tid = threadIdx.x;
  for (int ii = tid; ii < 2048; ii += 256) {
    int dl = ii >> 6;
    int d  = dz * 32 + dl;
    cn[dl * 68 + (ii & 63)] = ctxn[(size_t)b * 4096 + d * 64 + (ii & 63)] / dnm[b * 64 + d];
  }
  __syncthreads();
  const int c = tid;
  const float* wrow = Wo + (size_t)c * OQ + h * 64;
  float wv[64];
  for (int e = 0; e < 64; ++e) wv[e] = wrow[e];
  bf16* mrow = Mm + (size_t)b * CDIM * OQ + (size_t)c * OQ + h * 64 + dz * 32;
  for (int dl = 0; dl < 32; ++dl) {
    float a0 = 0.f, a1 = 0.f, a2 = 0.f, a3 = 0.f;
    for (int e = 0; e < 64; e += 4) {
      float4 c4 = *reinterpret_cast<const float4*>(&cn[dl * 68 + e]);
      a0 += wv[e]     * c4.x;
      a1 += wv[e + 1] * c4.y;
      a2 += wv[e + 2] * c4.z;
      a3 += wv[e + 3] * c4.w;
    }
    mrow[dl] = __float2bfloat16((a0 + a1) + (a2 + a3));
  }
}

// ---------------------------------------------------------------------------
// Kernel G2: y[b] (256x4096, fp32) = M_b (256x512) * q_smT^T + bo -> d_out
// ---------------------------------------------------------------------------
__global__ __launch_bounds__(256, 4) void gemm_out(
    const bf16* __restrict__ Mm, const bf16* __restrict__ qT,
    const float* __restrict__ bo, float* __restrict__ out) {
  __shared__ bf16 lsA[128 * 64];
  __shared__ bf16 lsB[128 * 64];
  const int tid = threadIdx.x;
  const int b  = blockIdx.z;
  const int cm = blockIdx.x;   // c-tile: 0..1
  const int nt = blockIdx.y;   // n-tile: 0..31
  const int lane = tid & 63;
  const int w    = tid >> 6;
  const int wm = w & 1, wn = w >> 1;
  const int l15 = lane & 15, quad = lane >> 4;

  const bf16* Ab = Mm + (size_t)b * CDIM * OQ + (size_t)cm * 128 * OQ;
  const bf16* Bb = qT + (size_t)b * NPIX * OQ + (size_t)nt * 128 * OQ;

  const int sr = lane >> 3;
  const int sc = lane & 7;

  floatx4 acc[4][4];
  const floatx4 zf = {0.f, 0.f, 0.f, 0.f};
  for (int i = 0; i < 4; ++i)
    for (int j = 0; j < 4; ++j) acc[i][j] = zf;

  for (int kb = 0; kb < OQ / 64; ++kb) {
    __syncthreads();
#pragma unroll
    for (int it = 0; it < 4; ++it) {
      const int r = w * 32 + it * 8 + sr;
      const int c16 = sc ^ (r & 7);
      gload16(Ab + (size_t)r * OQ + kb * 64 + c16 * 8, &lsA[(w * 4 + it) * 512]);
      gload16(Bb + (size_t)r * OQ + kb * 64 + c16 * 8, &lsB[(w * 4 + it) * 512]);
    }
    __syncthreads();
#pragma unroll
    for (int kk = 0; kk < 64; kk += 32) {
      bf16x8 af[4], bfr[4];
      for (int mi = 0; mi < 4; ++mi)
        af[mi] = lds_frag(lsA, wm * 64 + mi * 16 + l15, kk * 2 + quad * 16);
      for (int ni = 0; ni < 4; ++ni)
        bfr[ni] = lds_frag(lsB, wn * 64 + ni * 16 + l15, kk * 2 + quad * 16);
      for (int mi = 0; mi < 4; ++mi)
        for (int ni = 0; ni < 4; ++ni)
          acc[mi][ni] = __builtin_amdgcn_mfma_f32_16x16x32_bf16(af[mi], bfr[ni], acc[mi][ni], 0, 0, 0);
    }
  }

  // epilogue: direct fp32 stores (rows = c with stride NPIX, cols = n)
  const int row0 = cm * 128 + wm * 64;
  const int col0 = nt * 128 + wn * 64;
  float* outb = out + (size_t)b * CDIM * NPIX;
  for (int mi = 0; mi < 4; ++mi)
    for (int r = 0; r < 4; ++r) {
      int c = row0 + mi * 16 + quad * 4 + r;
      float bias = bo[c];
      float* orow = outb + (size_t)c * NPIX + col0;
      for (int ni = 0; ni < 4; ++ni)
        orow[ni * 16 + l15] = acc[mi][ni][r] + bias;
    }
}

// ---------------------------------------------------------------------------
// Host
// ---------------------------------------------------------------------------
extern "C" void kernel_launch(void* const* d_in, const int* in_sizes, int n_in,
                              void* d_out, int out_size, void* d_ws, size_t ws_size,
                              hipStream_t stream) {
  const float* x  = (const float*)d_in[0];
  const float* Wq = (const float*)d_in[1];
  const float* bq = (const float*)d_in[2];
  const float* Wk = (const float*)d_in[3];
  const float* bk = (const float*)d_in[4];
  const float* Wv = (const float*)d_in[5];
  const float* bv = (const float*)d_in[6];
  const float* Wo = (const float*)d_in[7];
  const float* bo = (const float*)d_in[8];
  float* out = (float*)d_out;

  const size_t pb_W   = (size_t)OTOT * CDIM * 2;   //   327,680 (once)
  const size_t pb_xT  = (size_t)NPIX * CDIM * 2;   // 2,097,152
  const size_t pb_qT  = (size_t)NPIX * OQ * 2;     // 4,194,304
  const size_t pb_kT  = (size_t)NPIX * KD * 2;     //   524,288
  const size_t pb_vT  = (size_t)NPIX * VD * 2;     //   524,288
  const size_t pb_ctx = (size_t)KD * VD * 4;       //    16,384
  const size_t pb_dnm = (size_t)KD * 4;            //       256
  const size_t pb_Mm  = (size_t)CDIM * OQ * 2;     //   262,144
  const size_t perB = pb_xT + pb_qT + pb_kT + pb_vT + pb_ctx + pb_dnm + pb_Mm;

  int CB = 32;
  while (CB > 1 && (size_t)CB * perB + pb_W > ws_size) CB >>= 1;

  char* ws = (char*)d_ws;
  bf16*  Wb   = (bf16*)ws;                                  ws += pb_W;
  bf16*  xT   = (bf16*)ws;                                  ws += (size_t)CB * pb_xT;
  bf16*  qT   = (bf16*)ws;                                  ws += (size_t)CB * pb_qT;
  bf16*  kT   = (bf16*)ws;                                  ws += (size_t)CB * pb_kT;
  bf16*  vT   = (bf16*)ws;                                  ws += (size_t)CB * pb_vT;
  float* ctxn = (float*)ws;                                 ws += (size_t)CB * pb_ctx;
  float* dnm  = (float*)ws;                                 ws += (size_t)CB * pb_dnm;
  bf16*  Mm   = (bf16*)ws;

  prep_w<<<dim3(80), 256, 0, stream>>>(Wq, Wk, Wv, Wb);

  for (int b0 = 0; b0 < BATCH; b0 += CB) {
    const float* x_c  = x   + (size_t)b0 * CDIM * NPIX;
    float*      out_c = out + (size_t)b0 * CDIM * NPIX;
    hipMemsetAsync(ctxn, 0, (size_t)CB * (pb_ctx + pb_dnm), stream);
    transpose_k<<<dim3(64, 4, CB), 256, 0, stream>>>(x_c, xT);
    gemm_qkv<<<dim3(32, 5, CB), 256, 0, stream>>>(xT, Wb, bq, bk, bv, qT, kT, vT);
    ctx_partial<<<dim3(16, CB), 256, 0, stream>>>(kT, vT, ctxn, dnm);
    mbuild<<<dim3(HEADS, CB, 2), 256, 0, stream>>>(ctxn, dnm, Wo, Mm);
    gemm_out<<<dim3(2, 32, CB), 256, 0, stream>>>(Mm, qT, bo, out_c);
  }
}

// Round 4
// 438.332 us; speedup vs baseline: 1.2170x; 1.0629x over previous
//
#include <hip/hip_runtime.h>
#include <hip/hip_bf16.h>
#include <stdint.h>

#define BATCH 32
#define CDIM  256
#define NPIX  4096
#define HEADS 8
#define KD    64
#define VD    64
#define OQ    512     // HEADS*KD
#define OTOT  640     // OQ + KD + VD

typedef __hip_bfloat16 bf16;
typedef __attribute__((ext_vector_type(8))) short bf16x8;   // MFMA A/B fragment (4 VGPRs)
typedef __attribute__((ext_vector_type(4))) float floatx4;  // MFMA C/D fragment

union pack8 { bf16 h[8]; uint4 u; };

__device__ inline uint4 cvt8(const float* __restrict__ s) {
  float4 f0 = *reinterpret_cast<const float4*>(s);
  float4 f1 = *reinterpret_cast<const float4*>(s + 4);
  pack8 t;
  t.h[0] = __float2bfloat16(f0.x); t.h[1] = __float2bfloat16(f0.y);
  t.h[2] = __float2bfloat16(f0.z); t.h[3] = __float2bfloat16(f0.w);
  t.h[4] = __float2bfloat16(f1.x); t.h[5] = __float2bfloat16(f1.y);
  t.h[6] = __float2bfloat16(f1.z); t.h[7] = __float2bfloat16(f1.w);
  return t.u;
}

// async global->LDS, 16B per lane; LDS dest arg is the wave-uniform base
__device__ inline void gload16(const bf16* g, bf16* l) {
  __builtin_amdgcn_global_load_lds(
      (const __attribute__((address_space(1))) void*)(g),
      (__attribute__((address_space(3))) void*)(l), 16, 0, 0);
}

// BK=32 tile: rows of 32 bf16 (64B) = 4 chunks of 16B. Swizzle: chunk ^= (row>>1)&3
// -> a 16-lane column read touches 8 bank-groups (2-way only = free, m136).
__device__ inline bf16x8 frag32(const bf16* buf, int row, int quad) {
  int ch = quad ^ ((row >> 1) & 3);
  return *reinterpret_cast<const bf16x8*>(
      reinterpret_cast<const char*>(buf) + row * 64 + ch * 16);
}

// epilogue scratch layout: rows of 64 bf16 viewed as 128B rows, XOR-swizzled
__device__ inline void ep_store(bf16* ep, int row, int colbyte, bf16 v) {
  int off = row * 128 + (colbyte ^ ((row & 7) << 4));
  *reinterpret_cast<bf16*>(reinterpret_cast<char*>(ep) + off) = v;
}

// ---------------------------------------------------------------------------
// Kernel P: pack Wq/Wk/Wv -> Wb bf16 [640][256]; Wo -> Wob bf16 [256][512]
// ---------------------------------------------------------------------------
__global__ __launch_bounds__(256) void prep_w(const float* __restrict__ Wq,
                                              const float* __restrict__ Wk,
                                              const float* __restrict__ Wv,
                                              const float* __restrict__ Wo,
                                              bf16* __restrict__ Wb,
                                              bf16* __restrict__ Wob) {
  int i = blockIdx.x * 256 + threadIdx.x;   // 20480 + 16384 chunks of 8
  if (i < 20480) {
    int o = i >> 5;
    int off = (i & 31) * 8;
    const float* src = (o < OQ)      ? (Wq + (size_t)o * CDIM + off)
                     : (o < OQ + KD) ? (Wk + (size_t)(o - OQ) * CDIM + off)
                                     : (Wv + (size_t)(o - OQ - KD) * CDIM + off);
    *reinterpret_cast<uint4*>(Wb + (size_t)o * CDIM + off) = cvt8(src);
  } else {
    int j = i - 20480;                      // Wo: 256 x 512 / 8 = 16384 chunks
    int c = j >> 6;
    int off = (j & 63) * 8;
    *reinterpret_cast<uint4*>(Wob + (size_t)c * OQ + off) =
        cvt8(Wo + (size_t)c * OQ + off);
  }
}

// ---------------------------------------------------------------------------
// Kernel T: x (b,C,N) fp32 -> xT (b,N,C) bf16, 64x64 tiles through LDS
// ---------------------------------------------------------------------------
__global__ __launch_bounds__(256) void transpose_k(const float* __restrict__ x,
                                                   bf16* __restrict__ xT) {
  __shared__ bf16 t[64 * 72];
  const int tid = threadIdx.x;
  const int b = blockIdx.z;
  const int n0 = blockIdx.x * 64;
  const int c0 = blockIdx.y * 64;
  const float* xb = x + (size_t)b * CDIM * NPIX;
  for (int p = 0; p < 2; ++p) {
    int cl = p * 32 + (tid >> 3);
    int no = (tid & 7) * 8;
    *reinterpret_cast<uint4*>(&t[cl * 72 + no]) =
        cvt8(xb + (size_t)(c0 + cl) * NPIX + n0 + no);
  }
  __syncthreads();
  bf16* xTb = xT + (size_t)b * NPIX * CDIM;
  for (int p = 0; p < 2; ++p) {
    int nl = p * 32 + (tid >> 3);
    int co = (tid & 7) * 8;
    pack8 tmp;
    for (int j = 0; j < 8; ++j) tmp.h[j] = t[(co + j) * 72 + nl];
    *reinterpret_cast<uint4*>(xTb + (size_t)(n0 + nl) * CDIM + c0 + co) = tmp.u;
  }
}

// ---------------------------------------------------------------------------
// 2-phase double-buffered staging (T3/T4 minimum): per K-step issue next
// tile's global_load_lds, counted s_waitcnt vmcnt(4), raw barrier, compute.
// LDS: 4 x 8KB buffers (A0,A1,B0,B1) = 32KB; epilogue reuses all 4 (8KB/wave).
// ---------------------------------------------------------------------------
#define STAGE32(Asrc, sA, Bsrc, sB, Abuf, Bbuf, k0)                          \
  {                                                                          \
    _Pragma("unroll")                                                        \
    for (int i_ = 0; i_ < 2; ++i_) {                                         \
      int cid_ = i_ * 256 + tid;                                             \
      int r_ = cid_ >> 2, cst_ = cid_ & 3;                                   \
      int cg_ = cst_ ^ ((r_ >> 1) & 3);                                      \
      gload16((Asrc) + (size_t)r_ * (sA) + (k0) + cg_ * 8,                   \
              (Abuf) + (i_ * 256 + w * 64) * 8);                             \
      gload16((Bsrc) + (size_t)r_ * (sB) + (k0) + cg_ * 8,                   \
              (Bbuf) + (i_ * 256 + w * 64) * 8);                             \
    }                                                                        \
  }

#define GEMM_STEP(Abuf, Bbuf)                                                \
  {                                                                          \
    bf16x8 af[4], bfr[4];                                                    \
    _Pragma("unroll")                                                        \
    for (int mi = 0; mi < 4; ++mi)                                           \
      af[mi] = frag32((Abuf), wm * 64 + mi * 16 + l15, quad);                \
    _Pragma("unroll")                                                        \
    for (int ni = 0; ni < 4; ++ni)                                           \
      bfr[ni] = frag32((Bbuf), wn * 64 + ni * 16 + l15, quad);               \
    _Pragma("unroll")                                                        \
    for (int mi = 0; mi < 4; ++mi)                                           \
      _Pragma("unroll")                                                      \
      for (int ni = 0; ni < 4; ++ni)                                         \
        acc[mi][ni] = __builtin_amdgcn_mfma_f32_16x16x32_bf16(               \
            af[mi], bfr[ni], acc[mi][ni], 0, 0, 0);                          \
  }

// ---------------------------------------------------------------------------
// Kernel G1: qkvT = xT (4096x256,bf16) * Wqkv^T (bf16)  -> (4096 x 640)
// ---------------------------------------------------------------------------
__global__ __launch_bounds__(256, 4) void gemm_qkv(
    const bf16* __restrict__ xT, const bf16* __restrict__ Wb,
    const float* __restrict__ bq, const float* __restrict__ bk,
    const float* __restrict__ bv,
    bf16* __restrict__ qT, bf16* __restrict__ kT, bf16* __restrict__ vT) {
  __shared__ bf16 sh[16384];   // A0 A1 B0 B1, 4096 bf16 each
  const int tid = threadIdx.x;
  const int b  = blockIdx.z;
  const int bm = blockIdx.x;   // n-tile (M dim): 0..31
  const int ot = blockIdx.y;   // o-tile (N dim): 0..4
  const int lane = tid & 63;
  const int w    = tid >> 6;
  const int wm = w & 1, wn = w >> 1;
  const int l15 = lane & 15, quad = lane >> 4;

  const bf16* Ab = xT + (size_t)b * NPIX * CDIM + (size_t)bm * 128 * CDIM;
  const bf16* Bb = Wb + (size_t)ot * 128 * CDIM;
  bf16* A0 = sh;  bf16* A1 = sh + 4096;  bf16* B0 = sh + 8192;  bf16* B1 = sh + 12288;

  floatx4 acc[4][4];
  const floatx4 zf = {0.f, 0.f, 0.f, 0.f};
  for (int i = 0; i < 4; ++i)
    for (int j = 0; j < 4; ++j) acc[i][j] = zf;

  STAGE32(Ab, CDIM, Bb, CDIM, A0, B0, 0);                 // prologue: kb=0
#pragma unroll
  for (int kb = 0; kb < 8; ++kb) {
    bf16* Ac = (kb & 1) ? A1 : A0;
    bf16* Bc = (kb & 1) ? B1 : B0;
    if (kb + 1 < 8) {
      bf16* An = (kb & 1) ? A0 : A1;
      bf16* Bn = (kb & 1) ? B0 : B1;
      STAGE32(Ab, CDIM, Bb, CDIM, An, Bn, (kb + 1) * 32);
      asm volatile("s_waitcnt vmcnt(4)" ::: "memory");
    } else {
      asm volatile("s_waitcnt vmcnt(0)" ::: "memory");
    }
    __builtin_amdgcn_sched_barrier(0);
    __builtin_amdgcn_s_barrier();
    GEMM_STEP(Ac, Bc);
    asm volatile("s_waitcnt lgkmcnt(0)" ::: "memory");
    __builtin_amdgcn_sched_barrier(0);
    __builtin_amdgcn_s_barrier();
  }

  // epilogue: this wave owns 64 rows (n) x 64 cols (o); 8KB scratch per wave
  bf16* ep = sh + w * 4096;
  const int obase = ot * 128 + wn * 64;

  if (obase < 512) {   // q head group: softmax over the 64 cols, no max-shift
    float bias[4];
    for (int ni = 0; ni < 4; ++ni) bias[ni] = bq[obase + ni * 16 + l15];
    for (int mi = 0; mi < 4; ++mi) {
      for (int r = 0; r < 4; ++r) {
        float e0 = __expf(acc[mi][0][r] + bias[0]);
        float e1 = __expf(acc[mi][1][r] + bias[1]);
        float e2 = __expf(acc[mi][2][r] + bias[2]);
        float e3 = __expf(acc[mi][3][r] + bias[3]);
        float s = (e0 + e1) + (e2 + e3);
        for (int off = 1; off < 16; off <<= 1) s += __shfl_xor(s, off);
        float inv = 1.0f / s;
        int lr = mi * 16 + quad * 4 + r;
        ep_store(ep, lr, ( 0 + l15) * 2, __float2bfloat16(e0 * inv));
        ep_store(ep, lr, (16 + l15) * 2, __float2bfloat16(e1 * inv));
        ep_store(ep, lr, (32 + l15) * 2, __float2bfloat16(e2 * inv));
        ep_store(ep, lr, (48 + l15) * 2, __float2bfloat16(e3 * inv));
      }
    }
  } else {             // k (wn==0) or v (wn==1): bias add, raw write
    const float* bp = (wn == 0) ? bk : bv;
    float bias[4];
    for (int ni = 0; ni < 4; ++ni) bias[ni] = bp[ni * 16 + l15];
    for (int mi = 0; mi < 4; ++mi)
      for (int r = 0; r < 4; ++r) {
        int lr = mi * 16 + quad * 4 + r;
        for (int ni = 0; ni < 4; ++ni)
          ep_store(ep, lr, (ni * 16 + l15) * 2,
                   __float2bfloat16(acc[mi][ni][r] + bias[ni]));
      }
  }
  __syncthreads();

  // cooperative coalesced copy-out of this wave's 64x64 region
  bf16* dst; int rstride;
  const int row0 = bm * 128 + wm * 64;
  if (obase < 512)      { dst = qT + (size_t)b * NPIX * OQ + (size_t)row0 * OQ + obase; rstride = OQ; }
  else if (obase == 512){ dst = kT + (size_t)b * NPIX * KD + (size_t)row0 * KD;         rstride = KD; }
  else                  { dst = vT + (size_t)b * NPIX * VD + (size_t)row0 * VD;         rstride = VD; }
  for (int p = 0; p < 8; ++p) {
    int lr = (lane >> 3) + p * 8;
    int cb = (lane & 7) * 16;   // byte column
    int off = lr * 128 + (cb ^ ((lr & 7) << 4));
    uint4 v = *reinterpret_cast<const uint4*>(reinterpret_cast<const char*>(ep) + off);
    *reinterpret_cast<uint4*>(dst + (size_t)lr * rstride + (cb >> 1)) = v;
  }
}

// ---------------------------------------------------------------------------
// Kernel CTX: partial ctx/denom per ci-slice -> plain stores (no atomics),
// into the dead xT region. ctxp[b][ci][64*64], dnp[b][ci][64].
// ---------------------------------------------------------------------------
#define XSTR (524288)          // floats per batch in the xT region (2MB)
#define DNPOFF (16 * 4096)     // dnp offset (floats) within a batch slice

__global__ __launch_bounds__(256) void ctx_partial(const bf16* __restrict__ kT,
                                                   const bf16* __restrict__ vT,
                                                   float* __restrict__ ctxp) {
  __shared__ float ek[16 * 68];
  __shared__ float vv[16 * 68];
  const int tid = threadIdx.x;
  const int b = blockIdx.y, ci = blockIdx.x;
  const int dg = tid >> 4, eg = tid & 15;
  float acc[4][4] = {};
  float dloc = 0.f;
  for (int nb = 0; nb < 16; ++nb) {
    const int n0 = ci * 256 + nb * 16;
    __syncthreads();
    if (tid < 128) {
      int r = tid >> 3, off = (tid & 7) * 8;
      pack8 p;
      p.u = *reinterpret_cast<const uint4*>(
          kT + (size_t)b * NPIX * KD + (size_t)(n0 + r) * KD + off);
      float4 f0, f1;
      f0.x = __expf(__bfloat162float(p.h[0])); f0.y = __expf(__bfloat162float(p.h[1]));
      f0.z = __expf(__bfloat162float(p.h[2])); f0.w = __expf(__bfloat162float(p.h[3]));
      f1.x = __expf(__bfloat162float(p.h[4])); f1.y = __expf(__bfloat162float(p.h[5]));
      f1.z = __expf(__bfloat162float(p.h[6])); f1.w = __expf(__bfloat162float(p.h[7]));
      *reinterpret_cast<float4*>(&ek[r * 68 + off])     = f0;
      *reinterpret_cast<float4*>(&ek[r * 68 + off + 4]) = f1;
    } else {
      int t2 = tid - 128;
      int r = t2 >> 3, off = (t2 & 7) * 8;
      pack8 p;
      p.u = *reinterpret_cast<const uint4*>(
          vT + (size_t)b * NPIX * VD + (size_t)(n0 + r) * VD + off);
      float4 f0, f1;
      f0.x = __bfloat162float(p.h[0]); f0.y = __bfloat162float(p.h[1]);
      f0.z = __bfloat162float(p.h[2]); f0.w = __bfloat162float(p.h[3]);
      f1.x = __bfloat162float(p.h[4]); f1.y = __bfloat162float(p.h[5]);
      f1.z = __bfloat162float(p.h[6]); f1.w = __bfloat162float(p.h[7]);
      *reinterpret_cast<float4*>(&vv[r * 68 + off])     = f0;
      *reinterpret_cast<float4*>(&vv[r * 68 + off + 4]) = f1;
    }
    __syncthreads();
    for (int nn = 0; nn < 16; ++nn) {
      float4 e4 = *reinterpret_cast<const float4*>(&ek[nn * 68 + dg * 4]);
      float4 v4 = *reinterpret_cast<const float4*>(&vv[nn * 68 + eg * 4]);
      acc[0][0] += e4.x * v4.x; acc[0][1] += e4.x * v4.y; acc[0][2] += e4.x * v4.z; acc[0][3] += e4.x * v4.w;
      acc[1][0] += e4.y * v4.x; acc[1][1] += e4.y * v4.y; acc[1][2] += e4.y * v4.z; acc[1][3] += e4.y * v4.w;
      acc[2][0] += e4.z * v4.x; acc[2][1] += e4.z * v4.y; acc[2][2] += e4.z * v4.z; acc[2][3] += e4.z * v4.w;
      acc[3][0] += e4.w * v4.x; acc[3][1] += e4.w * v4.y; acc[3][2] += e4.w * v4.z; acc[3][3] += e4.w * v4.w;
    }
    if (tid < 64) {
      for (int nn = 0; nn < 16; ++nn) dloc += ek[nn * 68 + tid];
    }
  }
  float* cp = ctxp + (size_t)b * XSTR + (size_t)ci * 4096;
  for (int i = 0; i < 4; ++i) {
    float4 f; f.x = acc[i][0]; f.y = acc[i][1]; f.z = acc[i][2]; f.w = acc[i][3];
    *reinterpret_cast<float4*>(&cp[(dg * 4 + i) * 64 + eg * 4]) = f;
  }
  if (tid < 64) ctxp[(size_t)b * XSTR + DNPOFF + ci * 64 + tid] = dloc;
}

// ---------------------------------------------------------------------------
// Kernel MBUILD: M[b][c][h*64+d] = sum_e Wo[c][h*64+e] * ctx[d][e]/denom[d]
//   folds the 16-slice reduction + denom; Wo read as prepacked bf16.
// ---------------------------------------------------------------------------
__global__ __launch_bounds__(256) void mbuild(const float* __restrict__ ctxp,
                                              const bf16* __restrict__ Wob,
                                              bf16* __restrict__ Mm) {
  __shared__ float cn[32 * 68];
  __shared__ float dn[32];
  const int h = blockIdx.x, b = blockIdx.y, dz = blockIdx.z;
  const int tid = threadIdx.x;
  const float* cb = ctxp + (size_t)b * XSTR;
  if (tid < 32) {
    int d = dz * 32 + tid;
    float s = 0.f;
    for (int ci = 0; ci < 16; ++ci) s += cb[DNPOFF + ci * 64 + d];
    dn[tid] = 1.0f / s;
  }
  __syncthreads();
  for (int ii = tid; ii < 2048; ii += 256) {
    int dl = ii >> 6, e = ii & 63;
    int d = dz * 32 + dl;
    float s = 0.f;
    for (int ci = 0; ci < 16; ++ci) s += cb[(size_t)ci * 4096 + d * 64 + e];
    cn[dl * 68 + e] = s * dn[dl];
  }
  __syncthreads();
  const int c = tid;
  const bf16* wrow = Wob + (size_t)c * OQ + h * 64;
  float wv[64];
  for (int t8 = 0; t8 < 8; ++t8) {
    pack8 p;
    p.u = *reinterpret_cast<const uint4*>(wrow + t8 * 8);
    for (int j = 0; j < 8; ++j) wv[t8 * 8 + j] = __bfloat162float(p.h[j]);
  }
  bf16* mrow = Mm + (size_t)b * CDIM * OQ + (size_t)c * OQ + h * 64 + dz * 32;
  for (int dl = 0; dl < 32; ++dl) {
    float a0 = 0.f, a1 = 0.f, a2 = 0.f, a3 = 0.f;
    for (int e = 0; e < 64; e += 4) {
      float4 c4 = *reinterpret_cast<const float4*>(&cn[dl * 68 + e]);
      a0 += wv[e]     * c4.x;
      a1 += wv[e + 1] * c4.y;
      a2 += wv[e + 2] * c4.z;
      a3 += wv[e + 3] * c4.w;
    }
    mrow[dl] = __float2bfloat16((a0 + a1) + (a2 + a3));
  }
}

// ---------------------------------------------------------------------------
// Kernel G2: y[b] (256x4096, fp32) = M_b (256x512) * q_smT^T + bo -> d_out
// ---------------------------------------------------------------------------
__global__ __launch_bounds__(256, 4) void gemm_out(
    const bf16* __restrict__ Mm, const bf16* __restrict__ qT,
    const float* __restrict__ bo, float* __restrict__ out) {
  __shared__ bf16 sh[16384];
  const int tid = threadIdx.x;
  const int b  = blockIdx.z;
  const int cm = blockIdx.x;   // c-tile: 0..1
  const int nt = blockIdx.y;   // n-tile: 0..31
  const int lane = tid & 63;
  const int w    = tid >> 6;
  const int wm = w & 1, wn = w >> 1;
  const int l15 = lane & 15, quad = lane >> 4;

  const bf16* Ab = Mm + (size_t)b * CDIM * OQ + (size_t)cm * 128 * OQ;
  const bf16* Bb = qT + (size_t)b * NPIX * OQ + (size_t)nt * 128 * OQ;
  bf16* A0 = sh;  bf16* A1 = sh + 4096;  bf16* B0 = sh + 8192;  bf16* B1 = sh + 12288;

  floatx4 acc[4][4];
  const floatx4 zf = {0.f, 0.f, 0.f, 0.f};
  for (int i = 0; i < 4; ++i)
    for (int j = 0; j < 4; ++j) acc[i][j] = zf;

  STAGE32(Ab, OQ, Bb, OQ, A0, B0, 0);
#pragma unroll
  for (int kb = 0; kb < 16; ++kb) {
    bf16* Ac = (kb & 1) ? A1 : A0;
    bf16* Bc = (kb & 1) ? B1 : B0;
    if (kb + 1 < 16) {
      bf16* An = (kb & 1) ? A0 : A1;
      bf16* Bn = (kb & 1) ? B0 : B1;
      STAGE32(Ab, OQ, Bb, OQ, An, Bn, (kb + 1) * 32);
      asm volatile("s_waitcnt vmcnt(4)" ::: "memory");
    } else {
      asm volatile("s_waitcnt vmcnt(0)" ::: "memory");
    }
    __builtin_amdgcn_sched_barrier(0);
    __builtin_amdgcn_s_barrier();
    GEMM_STEP(Ac, Bc);
    asm volatile("s_waitcnt lgkmcnt(0)" ::: "memory");
    __builtin_amdgcn_sched_barrier(0);
    __builtin_amdgcn_s_barrier();
  }

  // epilogue: direct fp32 stores (rows = c with stride NPIX, cols = n)
  const int row0 = cm * 128 + wm * 64;
  const int col0 = nt * 128 + wn * 64;
  float* outb = out + (size_t)b * CDIM * NPIX;
  for (int mi = 0; mi < 4; ++mi)
    for (int r = 0; r < 4; ++r) {
      int c = row0 + mi * 16 + quad * 4 + r;
      float bias = bo[c];
      float* orow = outb + (size_t)c * NPIX + col0;
      for (int ni = 0; ni < 4; ++ni)
        orow[ni * 16 + l15] = acc[mi][ni][r] + bias;
    }
}

// ---------------------------------------------------------------------------
// Host
// ---------------------------------------------------------------------------
extern "C" void kernel_launch(void* const* d_in, const int* in_sizes, int n_in,
                              void* d_out, int out_size, void* d_ws, size_t ws_size,
                              hipStream_t stream) {
  const float* x  = (const float*)d_in[0];
  const float* Wq = (const float*)d_in[1];
  const float* bq = (const float*)d_in[2];
  const float* Wk = (const float*)d_in[3];
  const float* bk = (const float*)d_in[4];
  const float* Wv = (const float*)d_in[5];
  const float* bv = (const float*)d_in[6];
  const float* Wo = (const float*)d_in[7];
  const float* bo = (const float*)d_in[8];
  float* out = (float*)d_out;

  const size_t pb_W   = (size_t)OTOT * CDIM * 2;   //   327,680 (once)
  const size_t pb_Wo  = (size_t)CDIM * OQ * 2;     //   262,144 (once)
  const size_t pb_xT  = (size_t)NPIX * CDIM * 2;   // 2,097,152 (ctxp aliases here)
  const size_t pb_qT  = (size_t)NPIX * OQ * 2;     // 4,194,304
  const size_t pb_kT  = (size_t)NPIX * KD * 2;     //   524,288
  const size_t pb_vT  = (size_t)NPIX * VD * 2;     //   524,288
  const size_t pb_Mm  = (size_t)CDIM * OQ * 2;     //   262,144
  const size_t perB = pb_xT + pb_qT + pb_kT + pb_vT + pb_Mm;

  int CB = 32;
  while (CB > 1 && (size_t)CB * perB + pb_W + pb_Wo > ws_size) CB >>= 1;

  char* ws = (char*)d_ws;
  bf16*  Wb   = (bf16*)ws;                                  ws += pb_W;
  bf16*  Wob  = (bf16*)ws;                                  ws += pb_Wo;
  bf16*  xT   = (bf16*)ws;                                  ws += (size_t)CB * pb_xT;
  bf16*  qT   = (bf16*)ws;                                  ws += (size_t)CB * pb_qT;
  bf16*  kT   = (bf16*)ws;                                  ws += (size_t)CB * pb_kT;
  bf16*  vT   = (bf16*)ws;                                  ws += (size_t)CB * pb_vT;
  bf16*  Mm   = (bf16*)ws;
  float* ctxp = (float*)xT;   // xT is dead after gemm_qkv; ctx partials live there

  prep_w<<<dim3(144), 256, 0, stream>>>(Wq, Wk, Wv, Wo, Wb, Wob);

  for (int b0 = 0; b0 < BATCH; b0 += CB) {
    const float* x_c  = x   + (size_t)b0 * CDIM * NPIX;
    float*      out_c = out + (size_t)b0 * CDIM * NPIX;
    transpose_k<<<dim3(64, 4, CB), 256, 0, stream>>>(x_c, xT);
    gemm_qkv<<<dim3(32, 5, CB), 256, 0, stream>>>(xT, Wb, bq, bk, bv, qT, kT, vT);
    ctx_partial<<<dim3(16, CB), 256, 0, stream>>>(kT, vT, ctxp);
    mbuild<<<dim3(HEADS, CB, 2), 256, 0, stream>>>(ctxp, Wob, Mm);
    gemm_out<<<dim3(2, 32, CB), 256, 0, stream>>>(Mm, qT, bo, out_c);
  }
}